// Round 19
// baseline (566.949 us; speedup 1.0000x reference)
//
#include <hip/hip_runtime.h>
#include <math.h>

#define NN 50000
#define NE 600000
#define DD 128
#define NL 4
#define NG 512
#define NT 10
#define NPAD 50176          // 392 * 128, padded row count for A_t
#define EPSF 1e-5f

typedef __bf16 bf16x8 __attribute__((ext_vector_type(8)));
typedef float f32x4 __attribute__((ext_vector_type(4)));

__device__ __forceinline__ unsigned short f2bf(float x) {
    union { float f; unsigned u; } v; v.f = x;
    unsigned r = v.u + 0x7FFFu + ((v.u >> 16) & 1u);
    return (unsigned short)(r >> 16);
}
__device__ __forceinline__ unsigned pack_bf2(float a, float b) {
    return (unsigned)f2bf(a) | ((unsigned)f2bf(b) << 16);
}
__device__ __forceinline__ float bf_lo(unsigned v) {
    union { unsigned u; float f; } w; w.u = (v & 0xFFFFu) << 16; return w.f;
}
__device__ __forceinline__ float bf_hi(unsigned v) {
    union { unsigned u; float f; } w; w.u = v & 0xFFFF0000u; return w.f;
}

// ---------------- CSR build ----------------
__global__ void k_count(const int* __restrict__ dst, int* __restrict__ deg,
                        float* __restrict__ dsum, int E) {
    int e = blockIdx.x * blockDim.x + threadIdx.x;
    if (e == 0) *dsum = 0.f;
    if (e < E) atomicAdd(&deg[dst[e]], 1);
}

// block partial sums + fused avg-log-degree reduction
__global__ void k_scan_part(const int* __restrict__ deg, int* __restrict__ part,
                            float* __restrict__ dsum, int n) {
    __shared__ int sm[256];
    int b = blockIdx.x, t = threadIdx.x;
    int base = b * 1024 + t * 4;
    int s = 0;
    float ls = 0.f;
    #pragma unroll
    for (int j = 0; j < 4; j++)
        if (base + j < n) { int d = deg[base + j]; s += d; ls += log1pf((float)d); }
    sm[t] = s;
    #pragma unroll
    for (int off = 32; off > 0; off >>= 1) ls += __shfl_down(ls, off);
    if ((t & 63) == 0) atomicAdd(dsum, ls);
    __syncthreads();
    for (int off = 128; off > 0; off >>= 1) {
        if (t < off) sm[t] += sm[t + off];
        __syncthreads();
    }
    if (t == 0) part[b] = sm[0];
}

// parallel top-level scan over <=64 block partials
__global__ void k_scan_top(const int* __restrict__ part, int* __restrict__ offs,
                           int* __restrict__ row_ptr, int nb, int n) {
    __shared__ int sm[64];
    int t = threadIdx.x;
    int v = (t < nb) ? part[t] : 0;
    sm[t] = v;
    __syncthreads();
    #pragma unroll
    for (int off = 1; off < 64; off <<= 1) {
        int y = (t >= off) ? sm[t - off] : 0;
        __syncthreads();
        sm[t] += y;
        __syncthreads();
    }
    if (t < nb) offs[t] = sm[t] - v;       // exclusive
    if (t == nb - 1) row_ptr[n] = sm[t];
}

// scan apply + fused degree scalars (k_scalars folded in: dsum complete by stream order)
__global__ void k_scan_apply(const int* __restrict__ deg, const int* __restrict__ offs,
                             int* __restrict__ row_ptr, int* __restrict__ cursor,
                             const float* __restrict__ dsum, float* __restrict__ inv_d,
                             float* __restrict__ amp, float* __restrict__ att, int n) {
    __shared__ int sm[256];
    int b = blockIdx.x, t = threadIdx.x;
    int base = b * 1024 + t * 4;
    int v[4]; int s = 0;
    #pragma unroll
    for (int j = 0; j < 4; j++) { v[j] = (base + j < n) ? deg[base + j] : 0; s += v[j]; }
    sm[t] = s;
    __syncthreads();
    for (int off = 1; off < 256; off <<= 1) {
        int y = (t >= off) ? sm[t - off] : 0;
        __syncthreads();
        sm[t] += y;
        __syncthreads();
    }
    int run = offs[b] + sm[t] - s;
    float delta = *dsum / (float)n;
    #pragma unroll
    for (int j = 0; j < 4; j++) {
        if (base + j < n) {
            row_ptr[base + j] = run; cursor[base + j] = run; run += v[j];
            float d = fmaxf((float)v[j], 1.f);
            float ld = log1pf(d);
            inv_d[base + j] = 1.f / d;
            amp[base + j] = ld / delta;
            att[base + j] = delta / ld;
        }
    }
}

__global__ void k_fill(const int* __restrict__ src, const int* __restrict__ dst,
                       int* __restrict__ cursor, int* __restrict__ csr_src, int E) {
    int e = blockIdx.x * blockDim.x + threadIdx.x;
    if (e < E) {
        int d = dst[e];
        int pos = atomicAdd(&cursor[d], 1);
        csr_src[pos] = src[e];
    }
}

// ---------------- node embedding (bf16 h only) ----------------
__global__ void k_emb(const float* __restrict__ x, const float* __restrict__ W,
                      const float* __restrict__ b, unsigned* __restrict__ hb2, int total2) {
    int i = blockIdx.x * blockDim.x + threadIdx.x;
    if (i >= total2) return;
    int node = i >> 6, c = (i & 63) * 2;
    float x0 = x[node * 3 + 0], x1 = x[node * 3 + 1], x2 = x[node * 3 + 2];
    float v0 = x0 * W[c] + x1 * W[DD + c] + x2 * W[2 * DD + c] + b[c];
    float v1 = x0 * W[c + 1] + x1 * W[DD + c + 1] + x2 * W[2 * DD + c + 1] + b[c + 1];
    hb2[i] = pack_bf2(v0, v1);
}

// -------- weight convert: conv_W [L,1536,128] f32 -> Bt2 [L][64 kc][3 j][128 col][8] bf16 ----
__global__ void k_wconv(const float* __restrict__ W, unsigned short* __restrict__ Bt2, int total) {
    int o = blockIdx.x * blockDim.x + threadIdx.x;
    if (o >= total) return;
    int l = o / 196608;
    int idx = o % 196608;
    int kc = idx / 3072;
    int rem = idx % 3072;
    int j = rem >> 10;
    int nn = (rem >> 3) & 127;
    int k8 = rem & 7;
    int k = kc * 8 + k8;
    Bt2[o] = f2bf(W[(size_t)l * 196608 + (size_t)(j * 512 + k) * 128 + nn]);
}

// ------ PNA aggregation (pair-interleave: 8 gathers in flight — proven best) ------
// A_t CONTIGUOUS layout: atw[kc4 = kc>>2][NPAD nodes][q = kc&3][4 uints]
// -> one wave GEMM A-load = 1KB fully contiguous (one DRAM page vs 4).
__global__ void k_agg(const unsigned* __restrict__ hb2, const int* __restrict__ row_ptr,
                      const int* __restrict__ csr_src, const float* __restrict__ inv_d,
                      unsigned* __restrict__ atw, float* __restrict__ bn_zero) {
    __shared__ unsigned ldsb[16 * 260];   // node stride 260 uints (bank-stagger)
    int tid = threadIdx.x;
    if (blockIdx.x == 0) bn_zero[tid] = 0.f;   // zero bn_sum[128]+bn_sq[128] for next gemm
    int w = tid >> 6, t = tid & 63;
    int node0 = blockIdx.x * 16;

    #pragma unroll 1
    for (int pp = 0; pp < 2; pp++) {
        int nlA = w * 4 + pp * 2;
        int nodeA = node0 + nlA, nodeB = nodeA + 1;
        int bgA = row_ptr[nodeA], enA = row_ptr[nodeA + 1];
        int bgB = row_ptr[nodeB], enB = row_ptr[nodeB + 1];
        float s1[2][2] = {{0.f,0.f},{0.f,0.f}};
        float s2[2][2] = {{0.f,0.f},{0.f,0.f}};
        float mn[2][2] = {{INFINITY,INFINITY},{INFINITY,INFINITY}};
        float mx[2][2] = {{-INFINITY,-INFINITY},{-INFINITY,-INFINITY}};
        auto ACC = [&](int ns, unsigned v) {
            float a = bf_lo(v), b = bf_hi(v);
            s1[ns][0] += a; s2[ns][0] += a * a;
            mn[ns][0] = fminf(mn[ns][0], a); mx[ns][0] = fmaxf(mx[ns][0], a);
            s1[ns][1] += b; s2[ns][1] += b * b;
            mn[ns][1] = fminf(mn[ns][1], b); mx[ns][1] = fmaxf(mx[ns][1], b);
        };
        int ea = bgA, eb = bgB;
        // paired main loop: 8 gathers in flight
        while (ea + 3 < enA && eb + 3 < enB) {
            int ia0 = csr_src[ea],     ia1 = csr_src[ea + 1];
            int ia2 = csr_src[ea + 2], ia3 = csr_src[ea + 3];
            int ib0 = csr_src[eb],     ib1 = csr_src[eb + 1];
            int ib2 = csr_src[eb + 2], ib3 = csr_src[eb + 3];
            unsigned va0 = hb2[(size_t)ia0 * 64 + t];
            unsigned va1 = hb2[(size_t)ia1 * 64 + t];
            unsigned va2 = hb2[(size_t)ia2 * 64 + t];
            unsigned va3 = hb2[(size_t)ia3 * 64 + t];
            unsigned vb0 = hb2[(size_t)ib0 * 64 + t];
            unsigned vb1 = hb2[(size_t)ib1 * 64 + t];
            unsigned vb2 = hb2[(size_t)ib2 * 64 + t];
            unsigned vb3 = hb2[(size_t)ib3 * 64 + t];
            ACC(0, va0); ACC(0, va1); ACC(0, va2); ACC(0, va3);
            ACC(1, vb0); ACC(1, vb1); ACC(1, vb2); ACC(1, vb3);
            ea += 4; eb += 4;
        }
        // drain node A
        for (; ea + 3 < enA; ea += 4) {
            int i0 = csr_src[ea], i1 = csr_src[ea + 1];
            int i2 = csr_src[ea + 2], i3 = csr_src[ea + 3];
            unsigned v0 = hb2[(size_t)i0 * 64 + t];
            unsigned v1 = hb2[(size_t)i1 * 64 + t];
            unsigned v2 = hb2[(size_t)i2 * 64 + t];
            unsigned v3 = hb2[(size_t)i3 * 64 + t];
            ACC(0, v0); ACC(0, v1); ACC(0, v2); ACC(0, v3);
        }
        for (; ea < enA; ea++) ACC(0, hb2[(size_t)csr_src[ea] * 64 + t]);
        // drain node B
        for (; eb + 3 < enB; eb += 4) {
            int i0 = csr_src[eb], i1 = csr_src[eb + 1];
            int i2 = csr_src[eb + 2], i3 = csr_src[eb + 3];
            unsigned v0 = hb2[(size_t)i0 * 64 + t];
            unsigned v1 = hb2[(size_t)i1 * 64 + t];
            unsigned v2 = hb2[(size_t)i2 * 64 + t];
            unsigned v3 = hb2[(size_t)i3 * 64 + t];
            ACC(1, v0); ACC(1, v1); ACC(1, v2); ACC(1, v3);
        }
        for (; eb < enB; eb++) ACC(1, hb2[(size_t)csr_src[eb] * 64 + t]);

        // finalize + LDS store
        #pragma unroll
        for (int ns = 0; ns < 2; ns++) {
            int node = (ns == 0) ? nodeA : nodeB;
            int nl = nlA + ns;
            int bg = (ns == 0) ? bgA : bgB;
            int en = (ns == 0) ? enA : enB;
            float id = inv_d[node];
            float meana = s1[ns][0] * id, meanb = s1[ns][1] * id;
            float sda = sqrtf(fmaxf(s2[ns][0] * id - meana * meana, 0.f) + EPSF);
            float sdb = sqrtf(fmaxf(s2[ns][1] * id - meanb * meanb, 0.f) + EPSF);
            float mna = mn[ns][0], mnb = mn[ns][1];
            float mxa = mx[ns][0], mxb = mx[ns][1];
            if (bg == en) { mna = 0.f; mxa = 0.f; mnb = 0.f; mxb = 0.f; }
            int base = nl * 260;
            ldsb[base + 0 * 64 + t] = pack_bf2(meana, meanb);
            ldsb[base + 1 * 64 + t] = pack_bf2(mna, mnb);
            ldsb[base + 2 * 64 + t] = pack_bf2(mxa, mxb);
            ldsb[base + 3 * 64 + t] = pack_bf2(sda, sdb);
        }
    }
    __syncthreads();
    // write phase: 1024 chunks of 16B; id -> {q2 = kc&3, node, kc4 = kc>>2};
    // consecutive 64 threads write 4KB fully contiguous.
    #pragma unroll
    for (int p = 0; p < 4; p++) {
        int id = p * 256 + tid;
        int q2 = id & 3;
        int node = (id >> 2) & 15;
        int kc4 = id >> 6;                 // 0..15
        int kc = kc4 * 4 + q2;
        int sec = kc >> 4, cw = kc & 15;
        const unsigned* s = &ldsb[node * 260 + sec * 64 + cw * 4];
        uint4 v = make_uint4(s[0], s[1], s[2], s[3]);
        *(uint4*)&atw[((size_t)kc4 * NPAD + node0 + node) * 16 + q2 * 4] = v;
    }
}

// --- MFMA GEMM (r16 structure, contiguous-A layout): zero-barrier, 3-stage register
// pipeline (distance-2, the measured regalloc-stable optimum), XCD swizzle, bf16 out.
// A wave-load is now 1KB contiguous (one page) instead of 4 segments 800KB apart. ---
__global__ __launch_bounds__(256, 2) void k_gemm_mfma(
    const unsigned short* __restrict__ At, const unsigned short* __restrict__ Bt2,
    const float* __restrict__ bias, const float* __restrict__ amp,
    const float* __restrict__ att, unsigned short* __restrict__ outb,
    float* __restrict__ bn_sum, float* __restrict__ bn_sq, int n) {
    int tid = threadIdx.x;
    int w = tid >> 6, lane = tid & 63;
    int quad = lane >> 4, l16 = lane & 15;
    int bid = blockIdx.x;
    int tile = (bid >> 5) * 8 + (bid & 7);
    int cg = (bid >> 3) & 3;
    if (tile >= 196) return;
    int c0 = cg * 32;
    int base = tile * 256 + w * 64;

    f32x4 acc[4][2][3];
    #pragma unroll
    for (int rt = 0; rt < 4; rt++)
        #pragma unroll
        for (int ct = 0; ct < 2; ct++)
            #pragma unroll
            for (int j = 0; j < 3; j++) acc[rt][ct][j] = (f32x4)(0.f);

    // At chunk (kc4, node, q) at ((kc4*NPAD + node)*4 + q)*8 shorts; iter it -> kc4 = it
    const unsigned short* pA = At + (size_t)(base + l16) * 32 + quad * 8;
    const unsigned short* pB = Bt2 + ((size_t)quad * 384 + c0 + l16) * 8;
    const size_t stepA = (size_t)NPAD * 32;
    const int stepB = 4 * 384 * 8;

    bf16x8 af0[4], af1[4], af2[4], bf0[2][3], bf1[2][3], bf2[2][3];
    auto loadA = [&](bf16x8* dst) {
        #pragma unroll
        for (int rt = 0; rt < 4; rt++) dst[rt] = *(const bf16x8*)(pA + rt * 512);
        pA += stepA;
    };
    auto loadB = [&](bf16x8 (*dst)[3]) {
        #pragma unroll
        for (int ct = 0; ct < 2; ct++)
            #pragma unroll
            for (int j = 0; j < 3; j++)
                dst[ct][j] = *(const bf16x8*)(pB + j * 1024 + ct * 128);
        pB += stepB;
    };
    auto domfma = [&](bf16x8* af, bf16x8 (*bf)[3]) {
        #pragma unroll
        for (int ct = 0; ct < 2; ct++)
            #pragma unroll
            for (int j = 0; j < 3; j++)
                #pragma unroll
                for (int rt = 0; rt < 4; rt++)
                    acc[rt][ct][j] = __builtin_amdgcn_mfma_f32_16x16x32_bf16(
                        af[rt], bf[ct][j], acc[rt][ct][j], 0, 0, 0);
    };

    loadA(af0); loadB(bf0);            // iter 0
    loadA(af1); loadB(bf1);            // iter 1
    #pragma unroll 1
    for (int it = 0; it < 15; it += 3) {
        loadA(af2); loadB(bf2);        // iter it+2
        domfma(af0, bf0);              // iter it
        loadA(af0); loadB(bf0);        // iter it+3
        domfma(af1, bf1);              // iter it+1
        loadA(af1); loadB(bf1);        // iter it+4
        domfma(af2, bf2);              // iter it+2
    }
    domfma(af0, bf0);                  // iter 15

    // epilogue: combine j via amp/att, bias, bf16 write, BN partials (from fp32 v)
    float psum[2] = {0.f, 0.f}, psq[2] = {0.f, 0.f};
    #pragma unroll
    for (int rt = 0; rt < 4; rt++) {
        #pragma unroll
        for (int reg = 0; reg < 4; reg++) {
            int row = base + rt * 16 + quad * 4 + reg;
            if (row < n) {
                float am = amp[row], at = att[row];
                #pragma unroll
                for (int ct = 0; ct < 2; ct++) {
                    int col = c0 + ct * 16 + l16;
                    float v = acc[rt][ct][0][reg] + am * acc[rt][ct][1][reg]
                            + at * acc[rt][ct][2][reg] + bias[col];
                    outb[(size_t)row * DD + col] = f2bf(v);
                    psum[ct] += v;
                    psq[ct] += v * v;
                }
            }
        }
    }
    #pragma unroll
    for (int ct = 0; ct < 2; ct++) {
        psum[ct] += __shfl_xor(psum[ct], 16, 64);
        psum[ct] += __shfl_xor(psum[ct], 32, 64);
        psq[ct]  += __shfl_xor(psq[ct], 16, 64);
        psq[ct]  += __shfl_xor(psq[ct], 32, 64);
    }
    if (quad == 0) {
        #pragma unroll
        for (int ct = 0; ct < 2; ct++) {
            int col = c0 + ct * 16 + l16;
            atomicAdd(&bn_sum[col], psum[ct]);
            atomicAdd(&bn_sq[col], psq[ct]);
        }
    }
}

// ------- BN stats+apply+relu+residual (bf16 outp + bf16 h; 8 channels/thread) --------
__global__ void k_bnapply(const unsigned* __restrict__ outb2, const float* __restrict__ bn_sum,
                          const float* __restrict__ bn_sq, const float* __restrict__ gamma,
                          const float* __restrict__ beta, unsigned* __restrict__ hb2,
                          int total8) {
    int i = blockIdx.x * blockDim.x + threadIdx.x;
    if (i >= total8) return;
    int c = (i & 15) * 8;
    const float invn = 1.f / (float)NN;
    uint4 ov = ((const uint4*)outb2)[i];
    uint4 hv = ((const uint4*)hb2)[i];
    unsigned ou[4] = {ov.x, ov.y, ov.z, ov.w};
    unsigned hu[4] = {hv.x, hv.y, hv.z, hv.w};
    unsigned ru[4];
    #pragma unroll
    for (int p = 0; p < 4; p++) {
        int c0 = c + p * 2;
        float mu0 = bn_sum[c0] * invn;
        float var0 = bn_sq[c0] * invn - mu0 * mu0;
        float sc0 = rsqrtf(var0 + EPSF) * gamma[c0];
        float sh0 = beta[c0] - mu0 * sc0;
        float mu1 = bn_sum[c0 + 1] * invn;
        float var1 = bn_sq[c0 + 1] * invn - mu1 * mu1;
        float sc1 = rsqrtf(var1 + EPSF) * gamma[c0 + 1];
        float sh1 = beta[c0 + 1] - mu1 * sc1;
        float v0 = fmaxf(bf_lo(ou[p]) * sc0 + sh0, 0.f) + bf_lo(hu[p]);
        float v1 = fmaxf(bf_hi(ou[p]) * sc1 + sh1, 0.f) + bf_hi(hu[p]);
        ru[p] = pack_bf2(v0, v1);
    }
    ((uint4*)hb2)[i] = make_uint4(ru[0], ru[1], ru[2], ru[3]);
}

// ---------------- pool + MLP (bf16 h input) ----------------
__global__ void k_pool_mlp(const unsigned* __restrict__ hb2, const int* __restrict__ batch,
                           const float* __restrict__ W1, const float* __restrict__ b1,
                           const float* __restrict__ W2, const float* __restrict__ b2,
                           const float* __restrict__ W3, const float* __restrict__ b3,
                           float* __restrict__ out, int n) {
    __shared__ float gvec[128];
    __shared__ float h1[64];
    __shared__ float h2[32];
    __shared__ int srange[2];
    int g = blockIdx.x;
    int t = threadIdx.x;
    if (t < 2) {
        int target = g + t;
        int lo = 0, hi = n;
        while (lo < hi) {
            int mid = (lo + hi) >> 1;
            if (batch[mid] < target) lo = mid + 1; else hi = mid;
        }
        srange[t] = lo;
    }
    __syncthreads();
    int s = srange[0], e = srange[1];
    int p = t >> 1, odd = t & 1;
    float acc = 0.f;
    for (int i = s; i < e; i++) {
        unsigned v = hb2[(size_t)i * 64 + p];
        acc += odd ? bf_hi(v) : bf_lo(v);
    }
    float cnt = fmaxf((float)(e - s), 1.f);
    gvec[t] = acc / cnt;
    __syncthreads();
    if (t < 64) {
        float a = b1[t];
        for (int k = 0; k < 128; k++) a += gvec[k] * W1[k * 64 + t];
        h1[t] = fmaxf(a, 0.f);
    }
    __syncthreads();
    if (t < 32) {
        float a = b2[t];
        for (int k = 0; k < 64; k++) a += h1[k] * W2[k * 32 + t];
        h2[t] = fmaxf(a, 0.f);
    }
    __syncthreads();
    if (t < 10) {
        float a = b3[t];
        for (int k = 0; k < 32; k++) a += h2[k] * W3[k * 10 + t];
        out[g * NT + t] = a;
    }
}

extern "C" void kernel_launch(void* const* d_in, const int* in_sizes, int n_in,
                              void* d_out, int out_size, void* d_ws, size_t ws_size,
                              hipStream_t stream) {
    const float* x      = (const float*)d_in[0];
    const int*   eidx   = (const int*)d_in[1];
    const int*   batch  = (const int*)d_in[2];
    const float* emb_W  = (const float*)d_in[3];
    const float* emb_b  = (const float*)d_in[4];
    const float* conv_W = (const float*)d_in[5];
    const float* conv_b = (const float*)d_in[6];
    const float* bn_g   = (const float*)d_in[7];
    const float* bn_b   = (const float*)d_in[8];
    const float* W1 = (const float*)d_in[9];
    const float* b1 = (const float*)d_in[10];
    const float* W2 = (const float*)d_in[11];
    const float* b2 = (const float*)d_in[12];
    const float* W3 = (const float*)d_in[13];
    const float* b3 = (const float*)d_in[14];
    float* out = (float*)d_out;

    const int* src = eidx;
    const int* dst = eidx + NE;

    char* p = (char*)d_ws;
    auto carve = [&](size_t bytes) {
        void* r = (void*)p;
        p += (bytes + 255) & ~(size_t)255;
        return r;
    };
    int* deg      = (int*)carve(NN * 4);
    int* row_ptr  = (int*)carve((NN + 1) * 4);
    int* cursor   = (int*)carve(NN * 4);
    int* csr_src  = (int*)carve(NE * 4);
    int* part     = (int*)carve(64 * 4);
    int* offs     = (int*)carve(64 * 4);
    float* inv_d  = (float*)carve(NN * 4);
    float* amp    = (float*)carve(NN * 4);
    float* att    = (float*)carve(NN * 4);
    float* dsum   = (float*)carve(4);
    float* bn_sum = (float*)carve(DD * 4);
    float* bn_sq  = (float*)carve(DD * 4);
    unsigned* hb2 = (unsigned*)carve((size_t)NN * 64 * 4);
    unsigned* At  = (unsigned*)carve((size_t)18 * NPAD * 64);   // 16 kc4 groups + 2 pad
    unsigned short* outb = (unsigned short*)carve((size_t)NN * DD * 2);
    unsigned short* Bt2 = (unsigned short*)carve(((size_t)NL * 196608 + 12288) * 2);

    hipMemsetAsync(deg, 0, NN * 4, stream);

    const int NSB = (NN + 1023) / 1024;   // 49 scan blocks
    k_count<<<(NE + 255) / 256, 256, 0, stream>>>(dst, deg, dsum, NE);
    k_scan_part<<<NSB, 256, 0, stream>>>(deg, part, dsum, NN);
    k_scan_top<<<1, 64, 0, stream>>>(part, offs, row_ptr, NSB, NN);
    k_scan_apply<<<NSB, 256, 0, stream>>>(deg, offs, row_ptr, cursor, dsum,
                                          inv_d, amp, att, NN);
    k_fill<<<(NE + 255) / 256, 256, 0, stream>>>(src, dst, cursor, csr_src, NE);
    k_emb<<<(NN * 64 + 255) / 256, 256, 0, stream>>>(x, emb_W, emb_b, hb2, NN * 64);
    k_wconv<<<(NL * 196608 + 255) / 256, 256, 0, stream>>>(conv_W, Bt2, NL * 196608);

    const int gemm_blocks = 800;   // 25 groups x 32; tile=(bid>>5)*8+(bid&7), cg=(bid>>3)&3
    for (int l = 0; l < NL; l++) {
        k_agg<<<NN / 16, 256, 0, stream>>>(hb2, row_ptr, csr_src, inv_d, At, bn_sum);
        k_gemm_mfma<<<gemm_blocks, 256, 0, stream>>>(
            (const unsigned short*)At, Bt2 + (size_t)l * 196608,
            conv_b + l * DD, amp, att, outb, bn_sum, bn_sq, NN);
        k_bnapply<<<(NN * 16 + 255) / 256, 256, 0, stream>>>(
            (const unsigned*)outb, bn_sum, bn_sq, bn_g + l * DD, bn_b + l * DD, hb2, NN * 16);
    }

    k_pool_mlp<<<NG, 128, 0, stream>>>(hb2, batch, W1, b1, W2, b2, W3, b3, out, NN);
}

// Round 20
// 550.996 us; speedup vs baseline: 1.0290x; 1.0290x over previous
//
#include <hip/hip_runtime.h>
#include <math.h>

#define NN 50000
#define NE 600000
#define DD 128
#define NL 4
#define NG 512
#define NT 10
#define NPAD 50176          // 392 * 128, padded row count for A_t
#define EPSF 1e-5f

typedef __bf16 bf16x8 __attribute__((ext_vector_type(8)));
typedef float f32x4 __attribute__((ext_vector_type(4)));

__device__ __forceinline__ unsigned short f2bf(float x) {
    union { float f; unsigned u; } v; v.f = x;
    unsigned r = v.u + 0x7FFFu + ((v.u >> 16) & 1u);
    return (unsigned short)(r >> 16);
}
__device__ __forceinline__ unsigned pack_bf2(float a, float b) {
    return (unsigned)f2bf(a) | ((unsigned)f2bf(b) << 16);
}
__device__ __forceinline__ float bf_lo(unsigned v) {
    union { unsigned u; float f; } w; w.u = (v & 0xFFFFu) << 16; return w.f;
}
__device__ __forceinline__ float bf_hi(unsigned v) {
    union { unsigned u; float f; } w; w.u = v & 0xFFFF0000u; return w.f;
}

// ---------------- CSR build ----------------
__global__ void k_count(const int* __restrict__ dst, int* __restrict__ deg,
                        float* __restrict__ dsum, int E) {
    int e = blockIdx.x * blockDim.x + threadIdx.x;
    if (e == 0) *dsum = 0.f;
    if (e < E) atomicAdd(&deg[dst[e]], 1);
}

// block partial sums + fused avg-log-degree reduction (k_delta folded in)
__global__ void k_scan_part(const int* __restrict__ deg, int* __restrict__ part,
                            float* __restrict__ dsum, int n) {
    __shared__ int sm[256];
    int b = blockIdx.x, t = threadIdx.x;
    int base = b * 1024 + t * 4;
    int s = 0;
    float ls = 0.f;
    #pragma unroll
    for (int j = 0; j < 4; j++)
        if (base + j < n) { int d = deg[base + j]; s += d; ls += log1pf((float)d); }
    sm[t] = s;
    #pragma unroll
    for (int off = 32; off > 0; off >>= 1) ls += __shfl_down(ls, off);
    if ((t & 63) == 0) atomicAdd(dsum, ls);
    __syncthreads();
    for (int off = 128; off > 0; off >>= 1) {
        if (t < off) sm[t] += sm[t + off];
        __syncthreads();
    }
    if (t == 0) part[b] = sm[0];
}

// parallel top-level scan over <=64 block partials
__global__ void k_scan_top(const int* __restrict__ part, int* __restrict__ offs,
                           int* __restrict__ row_ptr, int nb, int n) {
    __shared__ int sm[64];
    int t = threadIdx.x;
    int v = (t < nb) ? part[t] : 0;
    sm[t] = v;
    __syncthreads();
    #pragma unroll
    for (int off = 1; off < 64; off <<= 1) {
        int y = (t >= off) ? sm[t - off] : 0;
        __syncthreads();
        sm[t] += y;
        __syncthreads();
    }
    if (t < nb) offs[t] = sm[t] - v;       // exclusive
    if (t == nb - 1) row_ptr[n] = sm[t];
}

__global__ void k_scan_apply(const int* __restrict__ deg, const int* __restrict__ offs,
                             int* __restrict__ row_ptr, int* __restrict__ cursor, int n) {
    __shared__ int sm[256];
    int b = blockIdx.x, t = threadIdx.x;
    int base = b * 1024 + t * 4;
    int v[4]; int s = 0;
    #pragma unroll
    for (int j = 0; j < 4; j++) { v[j] = (base + j < n) ? deg[base + j] : 0; s += v[j]; }
    sm[t] = s;
    __syncthreads();
    for (int off = 1; off < 256; off <<= 1) {
        int y = (t >= off) ? sm[t - off] : 0;
        __syncthreads();
        sm[t] += y;
        __syncthreads();
    }
    int run = offs[b] + sm[t] - s;
    #pragma unroll
    for (int j = 0; j < 4; j++) {
        if (base + j < n) { row_ptr[base + j] = run; cursor[base + j] = run; run += v[j]; }
    }
}

__global__ void k_fill(const int* __restrict__ src, const int* __restrict__ dst,
                       int* __restrict__ cursor, int* __restrict__ csr_src, int E) {
    int e = blockIdx.x * blockDim.x + threadIdx.x;
    if (e < E) {
        int d = dst[e];
        int pos = atomicAdd(&cursor[d], 1);
        csr_src[pos] = src[e];
    }
}

// ---------------- degree scalars ----------------
__global__ void k_scalars(const int* __restrict__ deg, const float* __restrict__ dsum,
                          float* __restrict__ inv_d, float* __restrict__ amp,
                          float* __restrict__ att, int n) {
    int i = blockIdx.x * blockDim.x + threadIdx.x;
    if (i >= n) return;
    float delta = *dsum / (float)n;
    float d = fmaxf((float)deg[i], 1.f);
    float ld = log1pf(d);
    inv_d[i] = 1.f / d;
    amp[i] = ld / delta;
    att[i] = delta / ld;
}

// ---------------- node embedding (bf16 h only) ----------------
__global__ void k_emb(const float* __restrict__ x, const float* __restrict__ W,
                      const float* __restrict__ b, unsigned* __restrict__ hb2, int total2) {
    int i = blockIdx.x * blockDim.x + threadIdx.x;
    if (i >= total2) return;
    int node = i >> 6, c = (i & 63) * 2;
    float x0 = x[node * 3 + 0], x1 = x[node * 3 + 1], x2 = x[node * 3 + 2];
    float v0 = x0 * W[c] + x1 * W[DD + c] + x2 * W[2 * DD + c] + b[c];
    float v1 = x0 * W[c + 1] + x1 * W[DD + c + 1] + x2 * W[2 * DD + c + 1] + b[c + 1];
    hb2[i] = pack_bf2(v0, v1);
}

// -------- weight convert: conv_W [L,1536,128] f32 -> Bt2 [L][64 kc][3 j][128 col][8] bf16 ----
__global__ void k_wconv(const float* __restrict__ W, unsigned short* __restrict__ Bt2, int total) {
    int o = blockIdx.x * blockDim.x + threadIdx.x;
    if (o >= total) return;
    int l = o / 196608;
    int idx = o % 196608;
    int kc = idx / 3072;
    int rem = idx % 3072;
    int j = rem >> 10;
    int nn = (rem >> 3) & 127;
    int k8 = rem & 7;
    int k = kc * 8 + k8;
    Bt2[o] = f2bf(W[(size_t)l * 196608 + (size_t)(j * 512 + k) * 128 + nn]);
}

// ------ PNA aggregation (r14 pair-interleave: 8 gathers in flight — proven best) ------
// writes A_t k-major: atw[kchunk 0..63][NPAD nodes][4 uints]; kchunk = sec*16 + cbase.
// 4-segment-spread layout (r18) beats contiguous 1KB blocks (r19): channel parallelism
// wins over DRAM page locality for this streaming load.
__global__ void k_agg(const unsigned* __restrict__ hb2, const int* __restrict__ row_ptr,
                      const int* __restrict__ csr_src, const float* __restrict__ inv_d,
                      unsigned* __restrict__ atw, float* __restrict__ bn_zero) {
    __shared__ unsigned ldsb[16 * 260];   // node stride 260 uints (bank-stagger)
    int tid = threadIdx.x;
    if (blockIdx.x == 0) bn_zero[tid] = 0.f;   // zero bn_sum[128]+bn_sq[128] for next gemm
    int w = tid >> 6, t = tid & 63;
    int node0 = blockIdx.x * 16;

    #pragma unroll 1
    for (int pp = 0; pp < 2; pp++) {
        int nlA = w * 4 + pp * 2;
        int nodeA = node0 + nlA, nodeB = nodeA + 1;
        int bgA = row_ptr[nodeA], enA = row_ptr[nodeA + 1];
        int bgB = row_ptr[nodeB], enB = row_ptr[nodeB + 1];
        float s1[2][2] = {{0.f,0.f},{0.f,0.f}};
        float s2[2][2] = {{0.f,0.f},{0.f,0.f}};
        float mn[2][2] = {{INFINITY,INFINITY},{INFINITY,INFINITY}};
        float mx[2][2] = {{-INFINITY,-INFINITY},{-INFINITY,-INFINITY}};
        auto ACC = [&](int ns, unsigned v) {
            float a = bf_lo(v), b = bf_hi(v);
            s1[ns][0] += a; s2[ns][0] += a * a;
            mn[ns][0] = fminf(mn[ns][0], a); mx[ns][0] = fmaxf(mx[ns][0], a);
            s1[ns][1] += b; s2[ns][1] += b * b;
            mn[ns][1] = fminf(mn[ns][1], b); mx[ns][1] = fmaxf(mx[ns][1], b);
        };
        int ea = bgA, eb = bgB;
        // paired main loop: 8 gathers in flight
        while (ea + 3 < enA && eb + 3 < enB) {
            int ia0 = csr_src[ea],     ia1 = csr_src[ea + 1];
            int ia2 = csr_src[ea + 2], ia3 = csr_src[ea + 3];
            int ib0 = csr_src[eb],     ib1 = csr_src[eb + 1];
            int ib2 = csr_src[eb + 2], ib3 = csr_src[eb + 3];
            unsigned va0 = hb2[(size_t)ia0 * 64 + t];
            unsigned va1 = hb2[(size_t)ia1 * 64 + t];
            unsigned va2 = hb2[(size_t)ia2 * 64 + t];
            unsigned va3 = hb2[(size_t)ia3 * 64 + t];
            unsigned vb0 = hb2[(size_t)ib0 * 64 + t];
            unsigned vb1 = hb2[(size_t)ib1 * 64 + t];
            unsigned vb2 = hb2[(size_t)ib2 * 64 + t];
            unsigned vb3 = hb2[(size_t)ib3 * 64 + t];
            ACC(0, va0); ACC(0, va1); ACC(0, va2); ACC(0, va3);
            ACC(1, vb0); ACC(1, vb1); ACC(1, vb2); ACC(1, vb3);
            ea += 4; eb += 4;
        }
        // drain node A
        for (; ea + 3 < enA; ea += 4) {
            int i0 = csr_src[ea], i1 = csr_src[ea + 1];
            int i2 = csr_src[ea + 2], i3 = csr_src[ea + 3];
            unsigned v0 = hb2[(size_t)i0 * 64 + t];
            unsigned v1 = hb2[(size_t)i1 * 64 + t];
            unsigned v2 = hb2[(size_t)i2 * 64 + t];
            unsigned v3 = hb2[(size_t)i3 * 64 + t];
            ACC(0, v0); ACC(0, v1); ACC(0, v2); ACC(0, v3);
        }
        for (; ea < enA; ea++) ACC(0, hb2[(size_t)csr_src[ea] * 64 + t]);
        // drain node B
        for (; eb + 3 < enB; eb += 4) {
            int i0 = csr_src[eb], i1 = csr_src[eb + 1];
            int i2 = csr_src[eb + 2], i3 = csr_src[eb + 3];
            unsigned v0 = hb2[(size_t)i0 * 64 + t];
            unsigned v1 = hb2[(size_t)i1 * 64 + t];
            unsigned v2 = hb2[(size_t)i2 * 64 + t];
            unsigned v3 = hb2[(size_t)i3 * 64 + t];
            ACC(1, v0); ACC(1, v1); ACC(1, v2); ACC(1, v3);
        }
        for (; eb < enB; eb++) ACC(1, hb2[(size_t)csr_src[eb] * 64 + t]);

        // finalize + LDS store
        #pragma unroll
        for (int ns = 0; ns < 2; ns++) {
            int node = (ns == 0) ? nodeA : nodeB;
            int nl = nlA + ns;
            int bg = (ns == 0) ? bgA : bgB;
            int en = (ns == 0) ? enA : enB;
            float id = inv_d[node];
            float meana = s1[ns][0] * id, meanb = s1[ns][1] * id;
            float sda = sqrtf(fmaxf(s2[ns][0] * id - meana * meana, 0.f) + EPSF);
            float sdb = sqrtf(fmaxf(s2[ns][1] * id - meanb * meanb, 0.f) + EPSF);
            float mna = mn[ns][0], mnb = mn[ns][1];
            float mxa = mx[ns][0], mxb = mx[ns][1];
            if (bg == en) { mna = 0.f; mxa = 0.f; mnb = 0.f; mxb = 0.f; }
            int base = nl * 260;
            ldsb[base + 0 * 64 + t] = pack_bf2(meana, meanb);
            ldsb[base + 1 * 64 + t] = pack_bf2(mna, mnb);
            ldsb[base + 2 * 64 + t] = pack_bf2(mxa, mxb);
            ldsb[base + 3 * 64 + t] = pack_bf2(sda, sdb);
        }
    }
    __syncthreads();
    // write phase: 64 chunks x 16 nodes x 16B; lanes cover consecutive nodes -> 256B segs
    #pragma unroll
    for (int p = 0; p < 4; p++) {
        int id = p * 256 + tid;
        int node = id & 15, c = id >> 4;
        int sec = c >> 4, cb = c & 15;
        const unsigned* s = &ldsb[node * 260 + sec * 64 + cb * 4];
        uint4 v = make_uint4(s[0], s[1], s[2], s[3]);
        *(uint4*)&atw[((size_t)c * NPAD + node0 + node) * 4] = v;
    }
}

// --- MFMA GEMM (r16/r18-verified local optimum): zero-barrier, 3-stage register
// pipeline (distance-2 — deeper collapses in regalloc, r17), XCD swizzle, bf16 out. ---
__global__ __launch_bounds__(256, 2) void k_gemm_mfma(
    const unsigned short* __restrict__ At, const unsigned short* __restrict__ Bt2,
    const float* __restrict__ bias, const float* __restrict__ amp,
    const float* __restrict__ att, unsigned short* __restrict__ outb,
    float* __restrict__ bn_sum, float* __restrict__ bn_sq, int n) {
    int tid = threadIdx.x;
    int w = tid >> 6, lane = tid & 63;
    int quad = lane >> 4, l16 = lane & 15;
    int bid = blockIdx.x;
    int tile = (bid >> 5) * 8 + (bid & 7);
    int cg = (bid >> 3) & 3;
    if (tile >= 196) return;
    int c0 = cg * 32;
    int base = tile * 256 + w * 64;

    f32x4 acc[4][2][3];
    #pragma unroll
    for (int rt = 0; rt < 4; rt++)
        #pragma unroll
        for (int ct = 0; ct < 2; ct++)
            #pragma unroll
            for (int j = 0; j < 3; j++) acc[rt][ct][j] = (f32x4)(0.f);

    const unsigned short* pA = At + ((size_t)quad * NPAD + base + l16) * 8;
    const unsigned short* pB = Bt2 + ((size_t)quad * 384 + c0 + l16) * 8;
    const size_t stepA = (size_t)4 * NPAD * 8;
    const int stepB = 4 * 384 * 8;

    bf16x8 af0[4], af1[4], af2[4], bf0[2][3], bf1[2][3], bf2[2][3];
    auto loadA = [&](bf16x8* dst) {
        #pragma unroll
        for (int rt = 0; rt < 4; rt++) dst[rt] = *(const bf16x8*)(pA + rt * 128);
        pA += stepA;
    };
    auto loadB = [&](bf16x8 (*dst)[3]) {
        #pragma unroll
        for (int ct = 0; ct < 2; ct++)
            #pragma unroll
            for (int j = 0; j < 3; j++)
                dst[ct][j] = *(const bf16x8*)(pB + j * 1024 + ct * 128);
        pB += stepB;
    };
    auto domfma = [&](bf16x8* af, bf16x8 (*bf)[3]) {
        #pragma unroll
        for (int ct = 0; ct < 2; ct++)
            #pragma unroll
            for (int j = 0; j < 3; j++)
                #pragma unroll
                for (int rt = 0; rt < 4; rt++)
                    acc[rt][ct][j] = __builtin_amdgcn_mfma_f32_16x16x32_bf16(
                        af[rt], bf[ct][j], acc[rt][ct][j], 0, 0, 0);
    };

    loadA(af0); loadB(bf0);            // iter 0
    loadA(af1); loadB(bf1);            // iter 1
    #pragma unroll 1
    for (int it = 0; it < 15; it += 3) {
        loadA(af2); loadB(bf2);        // iter it+2
        domfma(af0, bf0);              // iter it
        loadA(af0); loadB(bf0);        // iter it+3
        domfma(af1, bf1);              // iter it+1
        loadA(af1); loadB(bf1);        // iter it+4
        domfma(af2, bf2);              // iter it+2
    }
    domfma(af0, bf0);                  // iter 15

    // epilogue: combine j via amp/att, bias, bf16 write, BN partials (from fp32 v)
    float psum[2] = {0.f, 0.f}, psq[2] = {0.f, 0.f};
    #pragma unroll
    for (int rt = 0; rt < 4; rt++) {
        #pragma unroll
        for (int reg = 0; reg < 4; reg++) {
            int row = base + rt * 16 + quad * 4 + reg;
            if (row < n) {
                float am = amp[row], at = att[row];
                #pragma unroll
                for (int ct = 0; ct < 2; ct++) {
                    int col = c0 + ct * 16 + l16;
                    float v = acc[rt][ct][0][reg] + am * acc[rt][ct][1][reg]
                            + at * acc[rt][ct][2][reg] + bias[col];
                    outb[(size_t)row * DD + col] = f2bf(v);
                    psum[ct] += v;
                    psq[ct] += v * v;
                }
            }
        }
    }
    #pragma unroll
    for (int ct = 0; ct < 2; ct++) {
        psum[ct] += __shfl_xor(psum[ct], 16, 64);
        psum[ct] += __shfl_xor(psum[ct], 32, 64);
        psq[ct]  += __shfl_xor(psq[ct], 16, 64);
        psq[ct]  += __shfl_xor(psq[ct], 32, 64);
    }
    if (quad == 0) {
        #pragma unroll
        for (int ct = 0; ct < 2; ct++) {
            int col = c0 + ct * 16 + l16;
            atomicAdd(&bn_sum[col], psum[ct]);
            atomicAdd(&bn_sq[col], psq[ct]);
        }
    }
}

// ------- BN stats+apply+relu+residual (bf16 outp + bf16 h; 8 channels/thread) --------
__global__ void k_bnapply(const unsigned* __restrict__ outb2, const float* __restrict__ bn_sum,
                          const float* __restrict__ bn_sq, const float* __restrict__ gamma,
                          const float* __restrict__ beta, unsigned* __restrict__ hb2,
                          int total8) {
    int i = blockIdx.x * blockDim.x + threadIdx.x;
    if (i >= total8) return;
    int c = (i & 15) * 8;
    const float invn = 1.f / (float)NN;
    uint4 ov = ((const uint4*)outb2)[i];
    uint4 hv = ((const uint4*)hb2)[i];
    unsigned ou[4] = {ov.x, ov.y, ov.z, ov.w};
    unsigned hu[4] = {hv.x, hv.y, hv.z, hv.w};
    unsigned ru[4];
    #pragma unroll
    for (int p = 0; p < 4; p++) {
        int c0 = c + p * 2;
        float mu0 = bn_sum[c0] * invn;
        float var0 = bn_sq[c0] * invn - mu0 * mu0;
        float sc0 = rsqrtf(var0 + EPSF) * gamma[c0];
        float sh0 = beta[c0] - mu0 * sc0;
        float mu1 = bn_sum[c0 + 1] * invn;
        float var1 = bn_sq[c0 + 1] * invn - mu1 * mu1;
        float sc1 = rsqrtf(var1 + EPSF) * gamma[c0 + 1];
        float sh1 = beta[c0 + 1] - mu1 * sc1;
        float v0 = fmaxf(bf_lo(ou[p]) * sc0 + sh0, 0.f) + bf_lo(hu[p]);
        float v1 = fmaxf(bf_hi(ou[p]) * sc1 + sh1, 0.f) + bf_hi(hu[p]);
        ru[p] = pack_bf2(v0, v1);
    }
    ((uint4*)hb2)[i] = make_uint4(ru[0], ru[1], ru[2], ru[3]);
}

// ---------------- pool + MLP (bf16 h input) ----------------
__global__ void k_pool_mlp(const unsigned* __restrict__ hb2, const int* __restrict__ batch,
                           const float* __restrict__ W1, const float* __restrict__ b1,
                           const float* __restrict__ W2, const float* __restrict__ b2,
                           const float* __restrict__ W3, const float* __restrict__ b3,
                           float* __restrict__ out, int n) {
    __shared__ float gvec[128];
    __shared__ float h1[64];
    __shared__ float h2[32];
    __shared__ int srange[2];
    int g = blockIdx.x;
    int t = threadIdx.x;
    if (t < 2) {
        int target = g + t;
        int lo = 0, hi = n;
        while (lo < hi) {
            int mid = (lo + hi) >> 1;
            if (batch[mid] < target) lo = mid + 1; else hi = mid;
        }
        srange[t] = lo;
    }
    __syncthreads();
    int s = srange[0], e = srange[1];
    int p = t >> 1, odd = t & 1;
    float acc = 0.f;
    for (int i = s; i < e; i++) {
        unsigned v = hb2[(size_t)i * 64 + p];
        acc += odd ? bf_hi(v) : bf_lo(v);
    }
    float cnt = fmaxf((float)(e - s), 1.f);
    gvec[t] = acc / cnt;
    __syncthreads();
    if (t < 64) {
        float a = b1[t];
        for (int k = 0; k < 128; k++) a += gvec[k] * W1[k * 64 + t];
        h1[t] = fmaxf(a, 0.f);
    }
    __syncthreads();
    if (t < 32) {
        float a = b2[t];
        for (int k = 0; k < 64; k++) a += h1[k] * W2[k * 32 + t];
        h2[t] = fmaxf(a, 0.f);
    }
    __syncthreads();
    if (t < 10) {
        float a = b3[t];
        for (int k = 0; k < 32; k++) a += h2[k] * W3[k * 10 + t];
        out[g * NT + t] = a;
    }
}

extern "C" void kernel_launch(void* const* d_in, const int* in_sizes, int n_in,
                              void* d_out, int out_size, void* d_ws, size_t ws_size,
                              hipStream_t stream) {
    const float* x      = (const float*)d_in[0];
    const int*   eidx   = (const int*)d_in[1];
    const int*   batch  = (const int*)d_in[2];
    const float* emb_W  = (const float*)d_in[3];
    const float* emb_b  = (const float*)d_in[4];
    const float* conv_W = (const float*)d_in[5];
    const float* conv_b = (const float*)d_in[6];
    const float* bn_g   = (const float*)d_in[7];
    const float* bn_b   = (const float*)d_in[8];
    const float* W1 = (const float*)d_in[9];
    const float* b1 = (const float*)d_in[10];
    const float* W2 = (const float*)d_in[11];
    const float* b2 = (const float*)d_in[12];
    const float* W3 = (const float*)d_in[13];
    const float* b3 = (const float*)d_in[14];
    float* out = (float*)d_out;

    const int* src = eidx;
    const int* dst = eidx + NE;

    char* p = (char*)d_ws;
    auto carve = [&](size_t bytes) {
        void* r = (void*)p;
        p += (bytes + 255) & ~(size_t)255;
        return r;
    };
    int* deg      = (int*)carve(NN * 4);
    int* row_ptr  = (int*)carve((NN + 1) * 4);
    int* cursor   = (int*)carve(NN * 4);
    int* csr_src  = (int*)carve(NE * 4);
    int* part     = (int*)carve(64 * 4);
    int* offs     = (int*)carve(64 * 4);
    float* inv_d  = (float*)carve(NN * 4);
    float* amp    = (float*)carve(NN * 4);
    float* att    = (float*)carve(NN * 4);
    float* dsum   = (float*)carve(4);
    float* bn_sum = (float*)carve(DD * 4);
    float* bn_sq  = (float*)carve(DD * 4);
    unsigned* hb2 = (unsigned*)carve((size_t)NN * 64 * 4);
    unsigned* At  = (unsigned*)carve((size_t)68 * NPAD * 16);   // 64 kchunks + 4 pad
    unsigned short* outb = (unsigned short*)carve((size_t)NN * DD * 2);
    unsigned short* Bt2 = (unsigned short*)carve(((size_t)NL * 196608 + 12288) * 2);

    hipMemsetAsync(deg, 0, NN * 4, stream);

    const int NSB = (NN + 1023) / 1024;   // 49 scan blocks
    k_count<<<(NE + 255) / 256, 256, 0, stream>>>(dst, deg, dsum, NE);
    k_scan_part<<<NSB, 256, 0, stream>>>(deg, part, dsum, NN);
    k_scan_top<<<1, 64, 0, stream>>>(part, offs, row_ptr, NSB, NN);
    k_scan_apply<<<NSB, 256, 0, stream>>>(deg, offs, row_ptr, cursor, NN);
    k_fill<<<(NE + 255) / 256, 256, 0, stream>>>(src, dst, cursor, csr_src, NE);
    k_scalars<<<(NN + 255) / 256, 256, 0, stream>>>(deg, dsum, inv_d, amp, att, NN);
    k_emb<<<(NN * 64 + 255) / 256, 256, 0, stream>>>(x, emb_W, emb_b, hb2, NN * 64);
    k_wconv<<<(NL * 196608 + 255) / 256, 256, 0, stream>>>(conv_W, Bt2, NL * 196608);

    const int gemm_blocks = 800;   // 25 groups x 32; tile=(bid>>5)*8+(bid&7), cg=(bid>>3)&3
    for (int l = 0; l < NL; l++) {
        k_agg<<<NN / 16, 256, 0, stream>>>(hb2, row_ptr, csr_src, inv_d, At, bn_sum);
        k_gemm_mfma<<<gemm_blocks, 256, 0, stream>>>(
            (const unsigned short*)At, Bt2 + (size_t)l * 196608,
            conv_b + l * DD, amp, att, outb, bn_sum, bn_sq, NN);
        k_bnapply<<<(NN * 16 + 255) / 256, 256, 0, stream>>>(
            (const unsigned*)outb, bn_sum, bn_sq, bn_g + l * DD, bn_b + l * DD, hb2, NN * 16);
    }

    k_pool_mlp<<<NG, 128, 0, stream>>>(hb2, batch, W1, b1, W2, b2, W3, b3, out, NN);
}